// Round 1
// 324.889 us; speedup vs baseline: 1.0698x; 1.0698x over previous
//
#include <hip/hip_runtime.h>
#include <hip/hip_bf16.h>

#define A_N 16
#define B_N 8192
#define O_N 128
#define ACT_N 16
#define H_N 128
#define NH_N 4
#define D_N 32
#define IN_N 144
#define NEGV -1e9f

typedef __attribute__((ext_vector_type(8))) short short8;
typedef __attribute__((ext_vector_type(4))) float floatx4;

// ---- bf16 helpers (RNE) -------------------------------------------------
static __device__ inline unsigned short f2bf(float f) {
    union { float f; unsigned u; } x{f};
    unsigned u = x.u + 0x7FFFu + ((x.u >> 16) & 1u);
    return (unsigned short)(u >> 16);
}
static __device__ inline unsigned pack_bf2(float a, float b) {
    union { float f; unsigned u; } xa{a}, xb{b};
    unsigned ua = xa.u + 0x7FFFu + ((xa.u >> 16) & 1u);
    unsigned ub = xb.u + 0x7FFFu + ((xb.u >> 16) & 1u);
    return (ua >> 16) | (ub & 0xFFFF0000u);
}
static __device__ inline float bf2f(unsigned short h) {
    union { unsigned u; float f; } x;
    x.u = ((unsigned)h) << 16;
    return x.f;
}
static __device__ inline float bflo(unsigned u) {
    union { unsigned u; float f; } x; x.u = u << 16; return x.f;
}
static __device__ inline float bfhi(unsigned u) {
    union { unsigned u; float f; } x; x.u = u & 0xFFFF0000u; return x.f;
}
static __device__ inline short8 ld_frag(const unsigned* p) {
    union { unsigned u[4]; short8 v; } x;
    uint2 lo = *(const uint2*)p;
    uint2 hi = *(const uint2*)(p + 2);
    x.u[0] = lo.x; x.u[1] = lo.y; x.u[2] = hi.x; x.u[3] = hi.y;
    return x.v;
}

// ---- misc small kernels -------------------------------------------------
__global__ __launch_bounds__(256) void k_zero(float* p, int n) {
    int i = blockIdx.x * 256 + threadIdx.x;
    if (i < n) p[i] = 0.f;
}

__global__ __launch_bounds__(256) void k_stats(const float* __restrict__ obs,
                                               const float* __restrict__ act,
                                               float* __restrict__ gsum,
                                               float* __restrict__ gsq) {
    __shared__ float ssum[IN_N];
    __shared__ float ssq[IN_N];
    int a = blockIdx.x >> 5;
    int r0 = (blockIdx.x & 31) * 256;
    int t = threadIdx.x;
    if (t < IN_N) { ssum[t] = 0.f; ssq[t] = 0.f; }
    __syncthreads();
    if (t < 128) {
        const float* p = obs + ((size_t)a * B_N + r0) * O_N + t;
        float s = 0.f, q = 0.f;
#pragma unroll 4
        for (int r = 0; r < 256; ++r) {
            float v = p[(size_t)r * O_N];
            s += v; q += v * v;
        }
        ssum[t] = s; ssq[t] = q;
    } else {
        int tt = t - 128;
        int f = tt & 15, rg = tt >> 4;
        const float* p = act + ((size_t)a * B_N + r0 + rg) * ACT_N + f;
        float s = 0.f, q = 0.f;
#pragma unroll 4
        for (int i = 0; i < 32; ++i) {
            float v = p[(size_t)i * 8 * ACT_N];
            s += v; q += v * v;
        }
        atomicAdd(&ssum[O_N + f], s);
        atomicAdd(&ssq[O_N + f], q);
    }
    __syncthreads();
    if (t < IN_N) {
        atomicAdd(&gsum[a * IN_N + t], ssum[t]);
        atomicAdd(&gsq[a * IN_N + t], ssq[t]);
    }
}

__global__ __launch_bounds__(256) void k_finalize(float* gsum, float* gsq) {
    int i = blockIdx.x * 256 + threadIdx.x;
    if (i < A_N * IN_N) {
        const float invB = 1.f / (float)B_N;
        float m = gsum[i] * invB;
        float v = fmaxf(gsq[i] * invB - m * m, 0.f);
        gsum[i] = m;
        gsq[i] = rsqrtf(v + 1e-5f);
    }
}

// ---- weight prep: fp32 -> bf16, transposed to [n][k/2] packed uints -----
// wt_l1 rows pre-scaled by rstd (BN folded into weights).
// wt_c2: Wc2 transposed to [a][o][h] fp32 for contiguous critic-tail reads.
#define L1E 393216
#define P1E 409600
#define P2E 417792
#define CRE 679936
#define C2E 712704
__global__ __launch_bounds__(256) void k_wprep(
    const float* __restrict__ W_sa, const float* __restrict__ W_s,
    const float* __restrict__ Wk, const float* __restrict__ Wsel,
    const float* __restrict__ Wv, const float* __restrict__ Wc1,
    const float* __restrict__ Wc2, const float* __restrict__ rstd,
    unsigned* __restrict__ wt_l1, unsigned* __restrict__ wt_p1,
    unsigned* __restrict__ wt_p2, unsigned* __restrict__ wt_cr,
    float* __restrict__ wt_c2) {
    int idx = blockIdx.x * 256 + threadIdx.x;
    if (idx < L1E) {
        int a = idx / 24576, rem = idx % 24576;
        int n = rem & 255, kp = rem >> 8;  // kp 0..95
        int k0 = 2 * kp, k1 = k0 + 1;
        float v0 = 0.f, v1 = 0.f;
        if (n < 128) {
            if (k0 < IN_N) v0 = W_sa[((size_t)a * IN_N + k0) * H_N + n] * rstd[a * IN_N + k0];
            if (k1 < IN_N) v1 = W_sa[((size_t)a * IN_N + k1) * H_N + n] * rstd[a * IN_N + k1];
        } else {
            int m = n - 128;
            if (k0 < O_N) v0 = W_s[((size_t)a * O_N + k0) * H_N + m] * rstd[a * IN_N + k0];
            if (k1 < O_N) v1 = W_s[((size_t)a * O_N + k1) * H_N + m] * rstd[a * IN_N + k1];
        }
        wt_l1[(size_t)a * 24576 + n * 96 + kp] = pack_bf2(v0, v1);
    } else if (idx < P1E) {
        int i2 = idx - L1E;
        int n = i2 & 255, kp = i2 >> 8;
        int k0 = 2 * kp;
        float v0, v1;
        if (n < 128) {
            const float* w = Wk + ((size_t)(n >> 5) * H_N) * D_N + (n & 31);
            v0 = w[(size_t)k0 * D_N]; v1 = w[(size_t)(k0 + 1) * D_N];
        } else {
            int m = n - 128;
            const float* w = Wv + ((size_t)(m >> 5) * H_N) * D_N + (m & 31);
            v0 = w[(size_t)k0 * D_N]; v1 = w[(size_t)(k0 + 1) * D_N];
        }
        wt_p1[n * 64 + kp] = pack_bf2(v0, v1);
    } else if (idx < P2E) {
        int i3 = idx - P1E;
        int n = i3 & 127, kp = i3 >> 7;
        int k0 = 2 * kp;
        const float* w = Wsel + ((size_t)(n >> 5) * H_N) * D_N + (n & 31);
        wt_p2[n * 64 + kp] = pack_bf2(w[(size_t)k0 * D_N], w[(size_t)(k0 + 1) * D_N]);
    } else if (idx < CRE) {
        int i4 = idx - P2E;
        int a = i4 >> 14, r = i4 & 16383;
        int n = r & 127, kp = r >> 7;
        int k0 = 2 * kp;
        const float* w = Wc1 + (size_t)a * 256 * H_N + n;
        wt_cr[(size_t)a * 16384 + n * 128 + kp] =
            pack_bf2(w[(size_t)k0 * H_N], w[(size_t)(k0 + 1) * H_N]);
    } else if (idx < C2E) {
        int i5 = idx - CRE;
        int a = i5 >> 11, rem = i5 & 2047;
        int oo = rem >> 7, h = rem & 127;
        wt_c2[i5] = Wc2[((size_t)a * H_N + h) * ACT_N + oo];
    }
}

// ---- folded biases: fb[0][a][c] = b_sa - sum(m*r*W_sa); fb[1] for se ----
__global__ __launch_bounds__(256) void k_bfold(
    const float* __restrict__ mean, const float* __restrict__ rstd,
    const float* __restrict__ W_sa, const float* __restrict__ W_s,
    const float* __restrict__ b_sa, const float* __restrict__ b_s,
    float* __restrict__ fb) {
    int a = blockIdx.x, c = threadIdx.x;
    float s = 0.f;
    if (c < 128) {
        for (int k = 0; k < IN_N; ++k)
            s += mean[a * IN_N + k] * rstd[a * IN_N + k] *
                 W_sa[((size_t)a * IN_N + k) * H_N + c];
        fb[a * 128 + c] = b_sa[a * H_N + c] - s;
    } else {
        int m = c - 128;
        for (int k = 0; k < O_N; ++k)
            s += mean[a * IN_N + k] * rstd[a * IN_N + k] *
                 W_s[((size_t)a * O_N + k) * H_N + m];
        fb[2048 + a * 128 + m] = b_s[a * H_N + m] - s;
    }
}

// ---- L1: z=0 -> sa (K=144 pad 160), z=1 -> se (K=128). BN pre-folded. ---
// staging vectorized: float4 global loads, uint2 LDS writes.
__global__ __launch_bounds__(256, 3) void k_l1(
    const float* __restrict__ obs, const float* __restrict__ act,
    const unsigned* __restrict__ wt_l1, const float* __restrict__ fb,
    unsigned short* __restrict__ sa_us, unsigned short* __restrict__ se_us,
    int b0g, int Bc) {
    __shared__ unsigned smem[(128 + 128) * 34];
    unsigned* Xs = smem;
    unsigned* Ws = smem + 128 * 34;

    int a = blockIdx.y;
    int z = blockIdx.z;
    int b0 = blockIdx.x * 128;
    int t = threadIdx.x;
    int wid = t >> 6, lane = t & 63, lm = lane & 15, lq = lane >> 4;
    int wrow = (wid & 1) * 64;
    int wcol = (wid >> 1) * 64;

    int kchunks = z ? 2 : 3;
    int kstop = z ? 128 : 160;
    const float* bias = fb + z * 2048 + a * 128;
    unsigned short* outp = z ? se_us : sa_us;

    floatx4 acc[4][4];
#pragma unroll
    for (int mt = 0; mt < 4; ++mt)
#pragma unroll
        for (int nt = 0; nt < 4; ++nt)
#pragma unroll
            for (int e = 0; e < 4; ++e) acc[mt][nt][e] = 0.f;

    const unsigned* WtA = wt_l1 + (size_t)a * 24576 + (size_t)(z * 128) * 96;

    for (int c = 0; c < kchunks; ++c) {
        int kk = c * 64;
        __syncthreads();
        // X: 128 rows x 16 float4 per chunk (8 iters/thread)
        for (int idx = t; idx < 128 * 16; idx += 256) {
            int r = idx >> 4, c4 = idx & 15;
            int k = kk + c4 * 4;
            size_t grow = (size_t)a * B_N + b0g + b0 + r;
            float4 v;
            if (k < O_N) v = *(const float4*)&obs[grow * O_N + k];
            else if (!z && k < IN_N) v = *(const float4*)&act[grow * ACT_N + (k - O_N)];
            else v = make_float4(0.f, 0.f, 0.f, 0.f);
            uint2* dst = (uint2*)&Xs[r * 34 + c4 * 2];
            *dst = make_uint2(pack_bf2(v.x, v.y), pack_bf2(v.z, v.w));
        }
        // W: 128 rows x 8 uint4 per chunk (4 iters/thread)
        for (int idx = t; idx < 128 * 8; idx += 256) {
            int n = idx >> 3, c4 = idx & 7;
            uint4 w = *(const uint4*)&WtA[(size_t)n * 96 + (kk >> 1) + c4 * 4];
            uint2* dst = (uint2*)&Ws[n * 34 + c4 * 4];
            dst[0] = make_uint2(w.x, w.y);
            dst[1] = make_uint2(w.z, w.w);
        }
        __syncthreads();
#pragma unroll
        for (int s = 0; s < 2; ++s) {
            if (kk + s * 32 >= kstop) break;
            short8 afr[4];
#pragma unroll
            for (int mt = 0; mt < 4; ++mt)
                afr[mt] = ld_frag(&Xs[(wrow + mt * 16 + lm) * 34 + s * 16 + lq * 4]);
#pragma unroll
            for (int nt = 0; nt < 4; ++nt) {
                short8 bfr = ld_frag(&Ws[(wcol + nt * 16 + lm) * 34 + s * 16 + lq * 4]);
#pragma unroll
                for (int mt = 0; mt < 4; ++mt)
                    acc[mt][nt] = __builtin_amdgcn_mfma_f32_16x16x32_bf16(
                        afr[mt], bfr, acc[mt][nt], 0, 0, 0);
            }
        }
    }

#pragma unroll
    for (int mt = 0; mt < 4; ++mt)
#pragma unroll
        for (int nt = 0; nt < 4; ++nt)
#pragma unroll
            for (int r = 0; r < 4; ++r) {
                int row = b0 + wrow + mt * 16 + lq * 4 + r;
                int col = wcol + nt * 16 + lm;
                float v = acc[mt][nt][r] + bias[col];
                v = v > 0.f ? v : 0.01f * v;
                outp[((size_t)a * Bc + row) * 128 + col] = f2bf(v);
            }
}

// ---- fused: keys|vals|sel GEMMs (LDS-only) + MFMA QK^T + scalar PV ------
// wave tile 64 rows x 32 cols: each global B-frag feeds 4 MFMAs (was 2),
// halving L2 weight-fragment traffic; staging via uint4 loads; se rows
// prefetched into registers before keys/vals MFMA phase (T14 split).
__global__ __launch_bounds__(256, 3) void k_fused(
    const unsigned* __restrict__ sa_u, const unsigned* __restrict__ se_u,
    const unsigned* __restrict__ wt_p1, const unsigned* __restrict__ wt_p2,
    const float* __restrict__ bv, unsigned short* __restrict__ other_us,
    int Bc) {
    __shared__ unsigned Xs[64 * 66];            // 16896 B (sa/se, then sel)
    __shared__ unsigned short keys_s[64 * 130]; // 16640 B (lg after QK^T)
    __shared__ unsigned short vals_s[64 * 136]; // 17408 B (16B-aligned rows)
    unsigned short* sel_s = (unsigned short*)Xs;

    int bg0 = blockIdx.x * 4;
    int t = threadIdx.x;
    int wid = t >> 6, lane = t & 63, lm = lane & 15, lq = lane >> 4;
    int wcol = wid * 32;

    // ---- stage sa rows [64][64 uints], row = agent*4 + bsub (uint4) ----
    for (int idx = t; idx < 64 * 16; idx += 256) {
        int r = idx >> 4, c4 = idx & 15;
        int a = r >> 2, b = bg0 + (r & 3);
        uint4 v = *(const uint4*)&sa_u[((size_t)a * Bc + b) * 64 + c4 * 4];
        uint2* dst = (uint2*)&Xs[r * 66 + c4 * 4];
        dst[0] = make_uint2(v.x, v.y);
        dst[1] = make_uint2(v.z, v.w);
    }
    // ---- issue se loads NOW; they land after the keys/vals phase ----
    uint4 seR[4];
#pragma unroll
    for (int ii = 0; ii < 4; ++ii) {
        int idx = t + ii * 256;
        int r = idx >> 4, c4 = idx & 15;
        int a = r >> 2, b = bg0 + (r & 3);
        seR[ii] = *(const uint4*)&se_u[((size_t)a * Bc + b) * 64 + c4 * 4];
    }
    __syncthreads();

    // ---- GEMM pass 0: keys, pass 1: vals (wave = 64 rows x 32 cols) ----
#pragma unroll
    for (int pass = 0; pass < 2; ++pass) {
        floatx4 acc[4][2];
#pragma unroll
        for (int mt = 0; mt < 4; ++mt)
#pragma unroll
            for (int nt = 0; nt < 2; ++nt)
#pragma unroll
                for (int e = 0; e < 4; ++e) acc[mt][nt][e] = 0.f;
        const unsigned* wbase = wt_p1 + (size_t)(pass * 128) * 64;
#pragma unroll
        for (int s = 0; s < 4; ++s) {
            short8 afr[4];
#pragma unroll
            for (int mt = 0; mt < 4; ++mt)
                afr[mt] = ld_frag(&Xs[(mt * 16 + lm) * 66 + s * 16 + lq * 4]);
#pragma unroll
            for (int nt = 0; nt < 2; ++nt) {
                int col = wcol + nt * 16 + lm;
                short8 bfr = ld_frag(wbase + (size_t)col * 64 + s * 16 + lq * 4);
#pragma unroll
                for (int mt = 0; mt < 4; ++mt)
                    acc[mt][nt] = __builtin_amdgcn_mfma_f32_16x16x32_bf16(
                        afr[mt], bfr, acc[mt][nt], 0, 0, 0);
            }
        }
#pragma unroll
        for (int mt = 0; mt < 4; ++mt)
#pragma unroll
            for (int nt = 0; nt < 2; ++nt)
#pragma unroll
                for (int r = 0; r < 4; ++r) {
                    int row = mt * 16 + lq * 4 + r;
                    int col = wcol + nt * 16 + lm;
                    float v = acc[mt][nt][r];
                    if (pass == 0) {
                        keys_s[row * 130 + col] = f2bf(v);
                    } else {
                        v += bv[col];
                        v = v > 0.f ? v : 0.01f * v;
                        vals_s[row * 136 + col] = f2bf(v);
                    }
                }
    }
    __syncthreads();

    // ---- write prefetched se rows (overwrite sa) ----
#pragma unroll
    for (int ii = 0; ii < 4; ++ii) {
        int idx = t + ii * 256;
        int r = idx >> 4, c4 = idx & 15;
        uint2* dst = (uint2*)&Xs[r * 66 + c4 * 4];
        dst[0] = make_uint2(seR[ii].x, seR[ii].y);
        dst[1] = make_uint2(seR[ii].z, seR[ii].w);
    }
    __syncthreads();

    // ---- GEMM2: sel ----
    {
        floatx4 acc[4][2];
#pragma unroll
        for (int mt = 0; mt < 4; ++mt)
#pragma unroll
            for (int nt = 0; nt < 2; ++nt)
#pragma unroll
                for (int e = 0; e < 4; ++e) acc[mt][nt][e] = 0.f;
#pragma unroll
        for (int s = 0; s < 4; ++s) {
            short8 afr[4];
#pragma unroll
            for (int mt = 0; mt < 4; ++mt)
                afr[mt] = ld_frag(&Xs[(mt * 16 + lm) * 66 + s * 16 + lq * 4]);
#pragma unroll
            for (int nt = 0; nt < 2; ++nt) {
                int col = wcol + nt * 16 + lm;
                short8 bfr = ld_frag(wt_p2 + (size_t)col * 64 + s * 16 + lq * 4);
#pragma unroll
                for (int mt = 0; mt < 4; ++mt)
                    acc[mt][nt] = __builtin_amdgcn_mfma_f32_16x16x32_bf16(
                        afr[mt], bfr, acc[mt][nt], 0, 0, 0);
            }
        }
        __syncthreads();  // all waves done reading Xs(se)
#pragma unroll
        for (int mt = 0; mt < 4; ++mt)
#pragma unroll
            for (int nt = 0; nt < 2; ++nt)
#pragma unroll
                for (int r = 0; r < 4; ++r) {
                    int row = mt * 16 + lq * 4 + r;
                    int col = wcol + nt * 16 + lm;
                    sel_s[row * 130 + col] = f2bf(acc[mt][nt][r]);
                }
    }
    __syncthreads();

    // ---- QK^T via MFMA: wave wid = bsub; one mfma per head n ----
    const unsigned* keysU = (const unsigned*)keys_s;
    floatx4 lgacc[4];
#pragma unroll
    for (int n = 0; n < 4; ++n) {
        short8 afr = ld_frag(&Xs[(lm * 4 + wid) * 65 + n * 16 + lq * 4]);     // sel
        short8 bfr = ld_frag(&keysU[(lm * 4 + wid) * 65 + n * 16 + lq * 4]);  // keys
        floatx4 z4 = {0.f, 0.f, 0.f, 0.f};
        lgacc[n] = __builtin_amdgcn_mfma_f32_16x16x32_bf16(afr, bfr, z4, 0, 0, 0);
    }
    __syncthreads();  // keys reads complete everywhere; reuse region for lg

    // lg layout: [(bsub*4+n)*16 + i][16 j] fp32 (16 KB in keys region)
    float* lgs = (float*)keys_s;
#pragma unroll
    for (int n = 0; n < 4; ++n)
#pragma unroll
        for (int r = 0; r < 4; ++r) {
            int i = lq * 4 + r;
            lgs[((wid * 4 + n) * 16 + i) * 16 + lm] =
                lgacc[n][r] * 0.17677669529663687f;
        }
    // wave-local readback (DS ops in-order per wave)

    int bsub = wid, n = (t >> 4) & 3, i = t & 15;
    float lg[16];
    {
        const float4* lgp = (const float4*)&lgs[((bsub * 4 + n) * 16 + i) * 16];
#pragma unroll
        for (int c = 0; c < 4; ++c) {
            float4 v = lgp[c];
            lg[4 * c] = v.x; lg[4 * c + 1] = v.y;
            lg[4 * c + 2] = v.z; lg[4 * c + 3] = v.w;
        }
    }
    lg[i] = NEGV;
    float m = lg[0];
#pragma unroll
    for (int j = 1; j < 16; ++j) m = fmaxf(m, lg[j]);
    float sum = 0.f;
#pragma unroll
    for (int j = 0; j < 16; ++j) { lg[j] = __expf(lg[j] - m); sum += lg[j]; }
    float inv = 1.f / sum;
#pragma unroll
    for (int j = 0; j < 16; ++j) lg[j] *= inv;

    // ---- PV: vals rows broadcast across agent lanes, uint4 reads ----
    const unsigned* valsU = (const unsigned*)vals_s;
    float ov[32];
#pragma unroll
    for (int u = 0; u < 32; ++u) ov[u] = 0.f;
#pragma unroll
    for (int j = 0; j < 16; ++j) {
        const uint4* vrow = (const uint4*)&valsU[(j * 4 + bsub) * 68 + n * 16];
        float w = lg[j];
#pragma unroll
        for (int c = 0; c < 4; ++c) {
            uint4 x = vrow[c];
            ov[8 * c + 0] = fmaf(w, bflo(x.x), ov[8 * c + 0]);
            ov[8 * c + 1] = fmaf(w, bfhi(x.x), ov[8 * c + 1]);
            ov[8 * c + 2] = fmaf(w, bflo(x.y), ov[8 * c + 2]);
            ov[8 * c + 3] = fmaf(w, bfhi(x.y), ov[8 * c + 3]);
            ov[8 * c + 4] = fmaf(w, bflo(x.z), ov[8 * c + 4]);
            ov[8 * c + 5] = fmaf(w, bfhi(x.z), ov[8 * c + 5]);
            ov[8 * c + 6] = fmaf(w, bflo(x.w), ov[8 * c + 6]);
            ov[8 * c + 7] = fmaf(w, bfhi(x.w), ov[8 * c + 7]);
        }
    }
    {
        uint4* orow = (uint4*)&other_us[((size_t)i * Bc + bg0 + bsub) * 128 + n * 32];
#pragma unroll
        for (int h = 0; h < 2; ++h) {
            uint4 o;
            o.x = pack_bf2(ov[16 * h + 0], ov[16 * h + 1]);
            o.y = pack_bf2(ov[16 * h + 2], ov[16 * h + 3]);
            o.z = pack_bf2(ov[16 * h + 4], ov[16 * h + 5]);
            o.w = pack_bf2(ov[16 * h + 6], ov[16 * h + 7]);
            orow[2 * h] = o;
            o.x = pack_bf2(ov[16 * h + 8], ov[16 * h + 9]);
            o.y = pack_bf2(ov[16 * h + 10], ov[16 * h + 11]);
            o.z = pack_bf2(ov[16 * h + 12], ov[16 * h + 13]);
            o.w = pack_bf2(ov[16 * h + 14], ov[16 * h + 15]);
            orow[2 * h + 1] = o;
        }
    }
}

// ---- critic: block 64 rows x 128 cols, wave 32x64, acc[2][4] ------------
__global__ __launch_bounds__(256, 3) void k_critic(
    const unsigned* __restrict__ se_u, const unsigned* __restrict__ other_u,
    const unsigned* __restrict__ wt_cr,
    const float* __restrict__ bc1, const float* __restrict__ actions,
    const float* __restrict__ wt_c2, const float* __restrict__ bc2,
    float* __restrict__ qout, int b0g, int Bc) {
    __shared__ unsigned smem[(64 + 128) * 34];
    unsigned* Xs = smem;
    unsigned* Ws = smem + 64 * 34;

    int a = blockIdx.y;
    int b0 = blockIdx.x * 64;
    int t = threadIdx.x;
    int wid = t >> 6, lane = t & 63, lm = lane & 15, lq = lane >> 4;
    int wrow = (wid & 1) * 32;
    int wcol = (wid >> 1) * 64;

    floatx4 acc[2][4];
#pragma unroll
    for (int mt = 0; mt < 2; ++mt)
#pragma unroll
        for (int nt = 0; nt < 4; ++nt)
#pragma unroll
            for (int e = 0; e < 4; ++e) acc[mt][nt][e] = 0.f;

    const unsigned* WtA = wt_cr + (size_t)a * 16384;

    for (int c = 0; c < 4; ++c) {
        int kk = c * 64;
        __syncthreads();
        const unsigned* src = (c < 2) ? se_u : other_u;
        int off = (c & 1) * 32;
        for (int idx = t; idx < 64 * 8; idx += 256) {
            int r = idx >> 3, c4 = idx & 7;
            uint4 v = *(const uint4*)&src[((size_t)a * Bc + b0 + r) * 64 + off + c4 * 4];
            uint2* dst = (uint2*)&Xs[r * 34 + c4 * 4];
            dst[0] = make_uint2(v.x, v.y);
            dst[1] = make_uint2(v.z, v.w);
        }
        for (int idx = t; idx < 128 * 8; idx += 256) {
            int n = idx >> 3, c4 = idx & 7;
            uint4 w = *(const uint4*)&WtA[(size_t)n * 128 + (kk >> 1) + c4 * 4];
            uint2* dst = (uint2*)&Ws[n * 34 + c4 * 4];
            dst[0] = make_uint2(w.x, w.y);
            dst[1] = make_uint2(w.z, w.w);
        }
        __syncthreads();
#pragma unroll
        for (int s = 0; s < 2; ++s) {
            short8 afr[2];
#pragma unroll
            for (int mt = 0; mt < 2; ++mt)
                afr[mt] = ld_frag(&Xs[(wrow + mt * 16 + lm) * 34 + s * 16 + lq * 4]);
#pragma unroll
            for (int nt = 0; nt < 4; ++nt) {
                short8 bfr = ld_frag(&Ws[(wcol + nt * 16 + lm) * 34 + s * 16 + lq * 4]);
#pragma unroll
                for (int mt = 0; mt < 2; ++mt)
                    acc[mt][nt] = __builtin_amdgcn_mfma_f32_16x16x32_bf16(
                        afr[mt], bfr, acc[mt][nt], 0, 0, 0);
            }
        }
    }

    __syncthreads();
    unsigned short* hbuf = (unsigned short*)smem;  // [64][132]
#pragma unroll
    for (int mt = 0; mt < 2; ++mt)
#pragma unroll
        for (int nt = 0; nt < 4; ++nt)
#pragma unroll
            for (int r = 0; r < 4; ++r) {
                int row = wrow + mt * 16 + lq * 4 + r;
                int col = wcol + nt * 16 + lm;
                float v = acc[mt][nt][r] + bc1[a * H_N + col];
                v = v > 0.f ? v : 0.01f * v;
                hbuf[row * 132 + col] = f2bf(v);
            }
    __syncthreads();
    if (t < 64) {
        size_t arow = (size_t)a * B_N + b0g + b0 + t;
        const float* ap = &actions[arow * ACT_N];
        float bestv = ap[0];
        int bi = 0;
        for (int o = 1; o < ACT_N; ++o) {
            float v = ap[o];
            if (v > bestv) { bestv = v; bi = o; }
        }
        float q = bc2[a * ACT_N + bi];
        const float4* w4p = (const float4*)&wt_c2[((size_t)a * ACT_N + bi) * H_N];
        const uint2* hp2 = (const uint2*)&hbuf[t * 132];
#pragma unroll
        for (int h4 = 0; h4 < 32; ++h4) {
            float4 w4 = w4p[h4];
            uint2 hh = hp2[h4];
            q = fmaf(bflo(hh.x), w4.x, q);
            q = fmaf(bfhi(hh.x), w4.y, q);
            q = fmaf(bflo(hh.y), w4.z, q);
            q = fmaf(bfhi(hh.y), w4.w, q);
        }
        qout[arow] = q;
    }
}

extern "C" void kernel_launch(void* const* d_in, const int* in_sizes, int n_in,
                              void* d_out, int out_size, void* d_ws, size_t ws_size,
                              hipStream_t stream) {
    const float* obs     = (const float*)d_in[0];
    const float* actions = (const float*)d_in[1];
    const float* W_sa    = (const float*)d_in[2];
    const float* b_sa    = (const float*)d_in[3];
    const float* W_s     = (const float*)d_in[4];
    const float* b_s     = (const float*)d_in[5];
    const float* Wk      = (const float*)d_in[6];
    const float* Wsel    = (const float*)d_in[7];
    const float* Wv      = (const float*)d_in[8];
    const float* bv      = (const float*)d_in[9];
    const float* Wc1     = (const float*)d_in[10];
    const float* bc1     = (const float*)d_in[11];
    const float* Wc2     = (const float*)d_in[12];
    const float* bc2     = (const float*)d_in[13];
    float* out = (float*)d_out;
    char* ws = (char*)d_ws;

    size_t o = 0;
    float* gsum = (float*)(ws + o); o += 2304 * 4;
    float* gsq  = (float*)(ws + o); o += 2304 * 4;
    unsigned* wt_l1 = (unsigned*)(ws + o); o += (size_t)393216 * 4;
    unsigned* wt_p1 = (unsigned*)(ws + o); o += (size_t)16384 * 4;
    unsigned* wt_p2 = (unsigned*)(ws + o); o += (size_t)8192 * 4;
    unsigned* wt_cr = (unsigned*)(ws + o); o += (size_t)262144 * 4;
    float* fb = (float*)(ws + o); o += (size_t)4096 * 4;
    float* wt_c2 = (float*)(ws + o); o += (size_t)32768 * 4;
    size_t fixed = o;

    int Bc = B_N;
    while (Bc > 128 && fixed + 12288ull * Bc > ws_size) Bc >>= 1;

    unsigned short* sa_us = (unsigned short*)(ws + o); o += (size_t)A_N * Bc * 128 * 2;
    unsigned short* se_us = (unsigned short*)(ws + o); o += (size_t)A_N * Bc * 128 * 2;
    unsigned short* ot_us = (unsigned short*)(ws + o); o += (size_t)A_N * Bc * 128 * 2;

    k_zero<<<dim3(18), 256, 0, stream>>>(gsum, 2 * A_N * IN_N);
    k_stats<<<dim3(A_N * 32), 256, 0, stream>>>(obs, actions, gsum, gsq);
    k_finalize<<<dim3(9), 256, 0, stream>>>(gsum, gsq);
    k_wprep<<<dim3(C2E / 256), 256, 0, stream>>>(W_sa, W_s, Wk, Wsel, Wv, Wc1, Wc2,
                                                 gsq, wt_l1, wt_p1, wt_p2, wt_cr, wt_c2);
    k_bfold<<<dim3(A_N), 256, 0, stream>>>(gsum, gsq, W_sa, W_s, b_sa, b_s, fb);

    for (int b0g = 0; b0g < B_N; b0g += Bc) {
        k_l1<<<dim3(Bc / 128, A_N, 2), 256, 0, stream>>>(
            obs, actions, wt_l1, fb, sa_us, se_us, b0g, Bc);
        k_fused<<<dim3(Bc / 4), 256, 0, stream>>>(
            (const unsigned*)sa_us, (const unsigned*)se_us, wt_p1, wt_p2, bv,
            ot_us, Bc);
        k_critic<<<dim3(Bc / 64, A_N), 256, 0, stream>>>(
            (const unsigned*)se_us, (const unsigned*)ot_us, wt_cr, bc1,
            actions, wt_c2, bc2, out, b0g, Bc);
    }
}

// Round 2
// 317.667 us; speedup vs baseline: 1.0942x; 1.0227x over previous
//
#include <hip/hip_runtime.h>
#include <hip/hip_bf16.h>

#define A_N 16
#define B_N 8192
#define O_N 128
#define ACT_N 16
#define H_N 128
#define NH_N 4
#define D_N 32
#define IN_N 144
#define NEGV -1e9f

typedef __attribute__((ext_vector_type(8))) short short8;
typedef __attribute__((ext_vector_type(4))) float floatx4;

// ---- bf16 helpers (RNE) -------------------------------------------------
static __device__ inline unsigned short f2bf(float f) {
    union { float f; unsigned u; } x{f};
    unsigned u = x.u + 0x7FFFu + ((x.u >> 16) & 1u);
    return (unsigned short)(u >> 16);
}
static __device__ inline unsigned pack_bf2(float a, float b) {
    union { float f; unsigned u; } xa{a}, xb{b};
    unsigned ua = xa.u + 0x7FFFu + ((xa.u >> 16) & 1u);
    unsigned ub = xb.u + 0x7FFFu + ((xb.u >> 16) & 1u);
    return (ua >> 16) | (ub & 0xFFFF0000u);
}
static __device__ inline float bf2f(unsigned short h) {
    union { unsigned u; float f; } x;
    x.u = ((unsigned)h) << 16;
    return x.f;
}
static __device__ inline float bflo(unsigned u) {
    union { unsigned u; float f; } x; x.u = u << 16; return x.f;
}
static __device__ inline float bfhi(unsigned u) {
    union { unsigned u; float f; } x; x.u = u & 0xFFFF0000u; return x.f;
}
static __device__ inline short8 ld_frag(const unsigned* p) {
    union { unsigned u[4]; short8 v; } x;
    uint2 lo = *(const uint2*)p;
    uint2 hi = *(const uint2*)(p + 2);
    x.u[0] = lo.x; x.u[1] = lo.y; x.u[2] = hi.x; x.u[3] = hi.y;
    return x.v;
}

// ---- misc small kernels -------------------------------------------------
__global__ __launch_bounds__(256) void k_zero(float* p, int n) {
    int i = blockIdx.x * 256 + threadIdx.x;
    if (i < n) p[i] = 0.f;
}

__global__ __launch_bounds__(256) void k_stats(const float* __restrict__ obs,
                                               const float* __restrict__ act,
                                               float* __restrict__ gsum,
                                               float* __restrict__ gsq) {
    __shared__ float ssum[IN_N];
    __shared__ float ssq[IN_N];
    int a = blockIdx.x >> 5;
    int r0 = (blockIdx.x & 31) * 256;
    int t = threadIdx.x;
    if (t < IN_N) { ssum[t] = 0.f; ssq[t] = 0.f; }
    __syncthreads();
    if (t < 128) {
        const float* p = obs + ((size_t)a * B_N + r0) * O_N + t;
        float s = 0.f, q = 0.f;
#pragma unroll 4
        for (int r = 0; r < 256; ++r) {
            float v = p[(size_t)r * O_N];
            s += v; q += v * v;
        }
        ssum[t] = s; ssq[t] = q;
    } else {
        int tt = t - 128;
        int f = tt & 15, rg = tt >> 4;
        const float* p = act + ((size_t)a * B_N + r0 + rg) * ACT_N + f;
        float s = 0.f, q = 0.f;
#pragma unroll 4
        for (int i = 0; i < 32; ++i) {
            float v = p[(size_t)i * 8 * ACT_N];
            s += v; q += v * v;
        }
        atomicAdd(&ssum[O_N + f], s);
        atomicAdd(&ssq[O_N + f], q);
    }
    __syncthreads();
    if (t < IN_N) {
        atomicAdd(&gsum[a * IN_N + t], ssum[t]);
        atomicAdd(&gsq[a * IN_N + t], ssq[t]);
    }
}

__global__ __launch_bounds__(256) void k_finalize(float* gsum, float* gsq) {
    int i = blockIdx.x * 256 + threadIdx.x;
    if (i < A_N * IN_N) {
        const float invB = 1.f / (float)B_N;
        float m = gsum[i] * invB;
        float v = fmaxf(gsq[i] * invB - m * m, 0.f);
        gsum[i] = m;
        gsq[i] = rsqrtf(v + 1e-5f);
    }
}

// ---- weight prep: fp32 -> bf16, transposed to [n][k/2] packed uints -----
// wt_l1 rows pre-scaled by rstd (BN folded into weights).
// wt_c2: Wc2 transposed to [a][o][h] fp32 for contiguous critic-tail reads.
#define L1E 393216
#define P1E 409600
#define P2E 417792
#define CRE 679936
#define C2E 712704
__global__ __launch_bounds__(256) void k_wprep(
    const float* __restrict__ W_sa, const float* __restrict__ W_s,
    const float* __restrict__ Wk, const float* __restrict__ Wsel,
    const float* __restrict__ Wv, const float* __restrict__ Wc1,
    const float* __restrict__ Wc2, const float* __restrict__ rstd,
    unsigned* __restrict__ wt_l1, unsigned* __restrict__ wt_p1,
    unsigned* __restrict__ wt_p2, unsigned* __restrict__ wt_cr,
    float* __restrict__ wt_c2) {
    int idx = blockIdx.x * 256 + threadIdx.x;
    if (idx < L1E) {
        int a = idx / 24576, rem = idx % 24576;
        int n = rem & 255, kp = rem >> 8;  // kp 0..95
        int k0 = 2 * kp, k1 = k0 + 1;
        float v0 = 0.f, v1 = 0.f;
        if (n < 128) {
            if (k0 < IN_N) v0 = W_sa[((size_t)a * IN_N + k0) * H_N + n] * rstd[a * IN_N + k0];
            if (k1 < IN_N) v1 = W_sa[((size_t)a * IN_N + k1) * H_N + n] * rstd[a * IN_N + k1];
        } else {
            int m = n - 128;
            if (k0 < O_N) v0 = W_s[((size_t)a * O_N + k0) * H_N + m] * rstd[a * IN_N + k0];
            if (k1 < O_N) v1 = W_s[((size_t)a * O_N + k1) * H_N + m] * rstd[a * IN_N + k1];
        }
        wt_l1[(size_t)a * 24576 + n * 96 + kp] = pack_bf2(v0, v1);
    } else if (idx < P1E) {
        int i2 = idx - L1E;
        int n = i2 & 255, kp = i2 >> 8;
        int k0 = 2 * kp;
        float v0, v1;
        if (n < 128) {
            const float* w = Wk + ((size_t)(n >> 5) * H_N) * D_N + (n & 31);
            v0 = w[(size_t)k0 * D_N]; v1 = w[(size_t)(k0 + 1) * D_N];
        } else {
            int m = n - 128;
            const float* w = Wv + ((size_t)(m >> 5) * H_N) * D_N + (m & 31);
            v0 = w[(size_t)k0 * D_N]; v1 = w[(size_t)(k0 + 1) * D_N];
        }
        wt_p1[n * 64 + kp] = pack_bf2(v0, v1);
    } else if (idx < P2E) {
        int i3 = idx - P1E;
        int n = i3 & 127, kp = i3 >> 7;
        int k0 = 2 * kp;
        const float* w = Wsel + ((size_t)(n >> 5) * H_N) * D_N + (n & 31);
        wt_p2[n * 64 + kp] = pack_bf2(w[(size_t)k0 * D_N], w[(size_t)(k0 + 1) * D_N]);
    } else if (idx < CRE) {
        int i4 = idx - P2E;
        int a = i4 >> 14, r = i4 & 16383;
        int n = r & 127, kp = r >> 7;
        int k0 = 2 * kp;
        const float* w = Wc1 + (size_t)a * 256 * H_N + n;
        wt_cr[(size_t)a * 16384 + n * 128 + kp] =
            pack_bf2(w[(size_t)k0 * H_N], w[(size_t)(k0 + 1) * H_N]);
    } else if (idx < C2E) {
        int i5 = idx - CRE;
        int a = i5 >> 11, rem = i5 & 2047;
        int oo = rem >> 7, h = rem & 127;
        wt_c2[i5] = Wc2[((size_t)a * H_N + h) * ACT_N + oo];
    }
}

// ---- folded biases: fb[0][a][c] = b_sa - sum(m*r*W_sa); fb[1] for se ----
__global__ __launch_bounds__(256) void k_bfold(
    const float* __restrict__ mean, const float* __restrict__ rstd,
    const float* __restrict__ W_sa, const float* __restrict__ W_s,
    const float* __restrict__ b_sa, const float* __restrict__ b_s,
    float* __restrict__ fb) {
    int a = blockIdx.x, c = threadIdx.x;
    float s = 0.f;
    if (c < 128) {
        for (int k = 0; k < IN_N; ++k)
            s += mean[a * IN_N + k] * rstd[a * IN_N + k] *
                 W_sa[((size_t)a * IN_N + k) * H_N + c];
        fb[a * 128 + c] = b_sa[a * H_N + c] - s;
    } else {
        int m = c - 128;
        for (int k = 0; k < O_N; ++k)
            s += mean[a * IN_N + k] * rstd[a * IN_N + k] *
                 W_s[((size_t)a * O_N + k) * H_N + m];
        fb[2048 + a * 128 + m] = b_s[a * H_N + m] - s;
    }
}

// ---- L1 merged: one block does BOTH sa (cols 0-127) and se (128-255). ---
// X tile K=160 (obs 128 | act 16 | pad 16); se weight rows are zero for
// k>=128 so the act columns contribute 0 to se. obs read ONCE (was twice).
// Output layout batch-major: row index (b_local*16 + a).
__global__ __launch_bounds__(512, 2) void k_l1(
    const float* __restrict__ obs, const float* __restrict__ act,
    const unsigned* __restrict__ wt_l1, const float* __restrict__ fb,
    unsigned short* __restrict__ sa_us, unsigned short* __restrict__ se_us,
    int b0g, int Bc) {
    __shared__ unsigned smem[(128 + 256) * 34];
    unsigned* Xs = smem;
    unsigned* Ws = smem + 128 * 34;

    int a = blockIdx.y;
    int b0 = blockIdx.x * 128;
    int t = threadIdx.x;
    int wid = t >> 6, lane = t & 63, lm = lane & 15, lq = lane >> 4;
    int wrow = (wid & 1) * 64;
    int wcol = (wid >> 1) * 64;  // 0,64 -> sa; 128,192 -> se

    floatx4 acc[4][4];
#pragma unroll
    for (int mt = 0; mt < 4; ++mt)
#pragma unroll
        for (int nt = 0; nt < 4; ++nt)
#pragma unroll
            for (int e = 0; e < 4; ++e) acc[mt][nt][e] = 0.f;

    const unsigned* WtA = wt_l1 + (size_t)a * 24576;

    for (int c = 0; c < 3; ++c) {
        int kk = c * 64;
        __syncthreads();
        // X: 128 rows x 16 float4 per chunk (4 iters/thread @512)
        for (int idx = t; idx < 128 * 16; idx += 512) {
            int r = idx >> 4, c4 = idx & 15;
            int k = kk + c4 * 4;
            size_t grow = (size_t)a * B_N + b0g + b0 + r;
            float4 v;
            if (k < O_N) v = *(const float4*)&obs[grow * O_N + k];
            else if (k < IN_N) v = *(const float4*)&act[grow * ACT_N + (k - O_N)];
            else v = make_float4(0.f, 0.f, 0.f, 0.f);
            uint2* dst = (uint2*)&Xs[r * 34 + c4 * 2];
            *dst = make_uint2(pack_bf2(v.x, v.y), pack_bf2(v.z, v.w));
        }
        // W: 256 n-rows x 8 uint4 per chunk (4 iters/thread @512)
        for (int idx = t; idx < 256 * 8; idx += 512) {
            int n = idx >> 3, c4 = idx & 7;
            uint4 w = *(const uint4*)&WtA[(size_t)n * 96 + (kk >> 1) + c4 * 4];
            uint2* dst = (uint2*)&Ws[n * 34 + c4 * 4];
            dst[0] = make_uint2(w.x, w.y);
            dst[1] = make_uint2(w.z, w.w);
        }
        __syncthreads();
#pragma unroll
        for (int s = 0; s < 2; ++s) {
            if (kk + s * 32 >= 160) break;
            short8 afr[4];
#pragma unroll
            for (int mt = 0; mt < 4; ++mt)
                afr[mt] = ld_frag(&Xs[(wrow + mt * 16 + lm) * 34 + s * 16 + lq * 4]);
#pragma unroll
            for (int nt = 0; nt < 4; ++nt) {
                short8 bfr = ld_frag(&Ws[(wcol + nt * 16 + lm) * 34 + s * 16 + lq * 4]);
#pragma unroll
                for (int mt = 0; mt < 4; ++mt)
                    acc[mt][nt] = __builtin_amdgcn_mfma_f32_16x16x32_bf16(
                        afr[mt], bfr, acc[mt][nt], 0, 0, 0);
            }
        }
    }

    int zsel = (wcol >= 128);
    unsigned short* outp = zsel ? se_us : sa_us;
    const float* bias = fb + zsel * 2048 + a * 128;
    int cbase = wcol & 127;
#pragma unroll
    for (int mt = 0; mt < 4; ++mt)
#pragma unroll
        for (int nt = 0; nt < 4; ++nt)
#pragma unroll
            for (int r = 0; r < 4; ++r) {
                int row = wrow + mt * 16 + lq * 4 + r;
                int col = cbase + nt * 16 + lm;
                float v = acc[mt][nt][r] + bias[col];
                v = v > 0.f ? v : 0.01f * v;
                outp[((size_t)(b0 + row) * 16 + a) * 128 + col] = f2bf(v);
            }
}

// ---- fused: keys|vals|sel GEMMs + MFMA QK^T + scalar PV -----------------
// batch-major layout: block reads ONE contiguous 16KB region per input.
// Tile row = bsub*16 + agent.
__global__ __launch_bounds__(256, 3) void k_fused(
    const unsigned* __restrict__ sa_u, const unsigned* __restrict__ se_u,
    const unsigned* __restrict__ wt_p1, const unsigned* __restrict__ wt_p2,
    const float* __restrict__ bv, unsigned short* __restrict__ other_us,
    int Bc) {
    __shared__ unsigned Xs[64 * 66];            // 16896 B (sa/se, then sel)
    __shared__ unsigned short keys_s[64 * 130]; // 16640 B (lg after QK^T)
    __shared__ unsigned short vals_s[64 * 136]; // 17408 B (16B-aligned rows)
    unsigned short* sel_s = (unsigned short*)Xs;

    int bg0 = blockIdx.x * 4;
    int t = threadIdx.x;
    int wid = t >> 6, lane = t & 63, lm = lane & 15, lq = lane >> 4;
    int wcol = wid * 32;

    const unsigned* sa_base = sa_u + (size_t)(bg0 * 16) * 64;
    const unsigned* se_base = se_u + (size_t)(bg0 * 16) * 64;

    // ---- stage sa: 64 contiguous rows, fully linear uint4 stream ----
    for (int idx = t; idx < 64 * 16; idx += 256) {
        int r = idx >> 4, c4 = idx & 15;
        uint4 v = *(const uint4*)&sa_base[(size_t)idx * 4];
        uint2* dst = (uint2*)&Xs[r * 66 + c4 * 4];
        dst[0] = make_uint2(v.x, v.y);
        dst[1] = make_uint2(v.z, v.w);
    }
    // ---- issue se loads NOW; they land after the keys/vals phase ----
    uint4 seR[4];
#pragma unroll
    for (int ii = 0; ii < 4; ++ii) {
        int idx = t + ii * 256;
        seR[ii] = *(const uint4*)&se_base[(size_t)idx * 4];
    }
    __syncthreads();

    // ---- GEMM pass 0: keys, pass 1: vals (wave = 64 rows x 32 cols) ----
#pragma unroll
    for (int pass = 0; pass < 2; ++pass) {
        floatx4 acc[4][2];
#pragma unroll
        for (int mt = 0; mt < 4; ++mt)
#pragma unroll
            for (int nt = 0; nt < 2; ++nt)
#pragma unroll
                for (int e = 0; e < 4; ++e) acc[mt][nt][e] = 0.f;
        const unsigned* wbase = wt_p1 + (size_t)(pass * 128) * 64;
#pragma unroll
        for (int s = 0; s < 4; ++s) {
            short8 afr[4];
#pragma unroll
            for (int mt = 0; mt < 4; ++mt)
                afr[mt] = ld_frag(&Xs[(mt * 16 + lm) * 66 + s * 16 + lq * 4]);
#pragma unroll
            for (int nt = 0; nt < 2; ++nt) {
                int col = wcol + nt * 16 + lm;
                short8 bfr = ld_frag(wbase + (size_t)col * 64 + s * 16 + lq * 4);
#pragma unroll
                for (int mt = 0; mt < 4; ++mt)
                    acc[mt][nt] = __builtin_amdgcn_mfma_f32_16x16x32_bf16(
                        afr[mt], bfr, acc[mt][nt], 0, 0, 0);
            }
        }
#pragma unroll
        for (int mt = 0; mt < 4; ++mt)
#pragma unroll
            for (int nt = 0; nt < 2; ++nt)
#pragma unroll
                for (int r = 0; r < 4; ++r) {
                    int row = mt * 16 + lq * 4 + r;
                    int col = wcol + nt * 16 + lm;
                    float v = acc[mt][nt][r];
                    if (pass == 0) {
                        keys_s[row * 130 + col] = f2bf(v);
                    } else {
                        v += bv[col];
                        v = v > 0.f ? v : 0.01f * v;
                        vals_s[row * 136 + col] = f2bf(v);
                    }
                }
    }
    __syncthreads();

    // ---- write prefetched se rows (overwrite sa) ----
#pragma unroll
    for (int ii = 0; ii < 4; ++ii) {
        int idx = t + ii * 256;
        int r = idx >> 4, c4 = idx & 15;
        uint2* dst = (uint2*)&Xs[r * 66 + c4 * 4];
        dst[0] = make_uint2(seR[ii].x, seR[ii].y);
        dst[1] = make_uint2(seR[ii].z, seR[ii].w);
    }
    __syncthreads();

    // ---- GEMM2: sel ----
    {
        floatx4 acc[4][2];
#pragma unroll
        for (int mt = 0; mt < 4; ++mt)
#pragma unroll
            for (int nt = 0; nt < 2; ++nt)
#pragma unroll
                for (int e = 0; e < 4; ++e) acc[mt][nt][e] = 0.f;
#pragma unroll
        for (int s = 0; s < 4; ++s) {
            short8 afr[4];
#pragma unroll
            for (int mt = 0; mt < 4; ++mt)
                afr[mt] = ld_frag(&Xs[(mt * 16 + lm) * 66 + s * 16 + lq * 4]);
#pragma unroll
            for (int nt = 0; nt < 2; ++nt) {
                int col = wcol + nt * 16 + lm;
                short8 bfr = ld_frag(wt_p2 + (size_t)col * 64 + s * 16 + lq * 4);
#pragma unroll
                for (int mt = 0; mt < 4; ++mt)
                    acc[mt][nt] = __builtin_amdgcn_mfma_f32_16x16x32_bf16(
                        afr[mt], bfr, acc[mt][nt], 0, 0, 0);
            }
        }
        __syncthreads();  // all waves done reading Xs(se)
#pragma unroll
        for (int mt = 0; mt < 4; ++mt)
#pragma unroll
            for (int nt = 0; nt < 2; ++nt)
#pragma unroll
                for (int r = 0; r < 4; ++r) {
                    int row = mt * 16 + lq * 4 + r;
                    int col = wcol + nt * 16 + lm;
                    sel_s[row * 132 + col] = f2bf(acc[mt][nt][r]);
                }
    }
    __syncthreads();

    // ---- QK^T via MFMA: wave wid = bsub; one mfma per head n ----
    // tile row = bsub*16 + agent -> A/B row for agent lm is wid*16+lm.
    const unsigned* keysU = (const unsigned*)keys_s;
    floatx4 lgacc[4];
#pragma unroll
    for (int n = 0; n < 4; ++n) {
        short8 afr = ld_frag(&Xs[(wid * 16 + lm) * 66 + n * 16 + lq * 4]);     // sel
        short8 bfr = ld_frag(&keysU[(wid * 16 + lm) * 65 + n * 16 + lq * 4]);  // keys
        floatx4 z4 = {0.f, 0.f, 0.f, 0.f};
        lgacc[n] = __builtin_amdgcn_mfma_f32_16x16x32_bf16(afr, bfr, z4, 0, 0, 0);
    }
    __syncthreads();  // keys reads complete everywhere; reuse region for lg

    // lg layout: [(bsub*4+n)*16 + i][16 j] fp32 (16 KB in keys region)
    float* lgs = (float*)keys_s;
#pragma unroll
    for (int n = 0; n < 4; ++n)
#pragma unroll
        for (int r = 0; r < 4; ++r) {
            int i = lq * 4 + r;
            lgs[((wid * 4 + n) * 16 + i) * 16 + lm] =
                lgacc[n][r] * 0.17677669529663687f;
        }
    // wave-local readback (DS ops in-order per wave)

    int bsub = wid, n = (t >> 4) & 3, i = t & 15;
    float lg[16];
    {
        const float4* lgp = (const float4*)&lgs[((bsub * 4 + n) * 16 + i) * 16];
#pragma unroll
        for (int c = 0; c < 4; ++c) {
            float4 v = lgp[c];
            lg[4 * c] = v.x; lg[4 * c + 1] = v.y;
            lg[4 * c + 2] = v.z; lg[4 * c + 3] = v.w;
        }
    }
    lg[i] = NEGV;
    float m = lg[0];
#pragma unroll
    for (int j = 1; j < 16; ++j) m = fmaxf(m, lg[j]);
    float sum = 0.f;
#pragma unroll
    for (int j = 0; j < 16; ++j) { lg[j] = __expf(lg[j] - m); sum += lg[j]; }
    float inv = 1.f / sum;
#pragma unroll
    for (int j = 0; j < 16; ++j) lg[j] *= inv;

    // ---- PV: vals row for (agent j, bsub) = bsub*16 + j ----
    const unsigned* valsU = (const unsigned*)vals_s;
    float ov[32];
#pragma unroll
    for (int u = 0; u < 32; ++u) ov[u] = 0.f;
#pragma unroll
    for (int j = 0; j < 16; ++j) {
        const uint4* vrow = (const uint4*)&valsU[(bsub * 16 + j) * 68 + n * 16];
        float w = lg[j];
#pragma unroll
        for (int c = 0; c < 4; ++c) {
            uint4 x = vrow[c];
            ov[8 * c + 0] = fmaf(w, bflo(x.x), ov[8 * c + 0]);
            ov[8 * c + 1] = fmaf(w, bfhi(x.x), ov[8 * c + 1]);
            ov[8 * c + 2] = fmaf(w, bflo(x.y), ov[8 * c + 2]);
            ov[8 * c + 3] = fmaf(w, bfhi(x.y), ov[8 * c + 3]);
            ov[8 * c + 4] = fmaf(w, bflo(x.z), ov[8 * c + 4]);
            ov[8 * c + 5] = fmaf(w, bfhi(x.z), ov[8 * c + 5]);
            ov[8 * c + 6] = fmaf(w, bflo(x.w), ov[8 * c + 6]);
            ov[8 * c + 7] = fmaf(w, bfhi(x.w), ov[8 * c + 7]);
        }
    }
    {
        uint4* orow = (uint4*)&other_us[((size_t)(bg0 + bsub) * 16 + i) * 128 + n * 32];
#pragma unroll
        for (int h = 0; h < 2; ++h) {
            uint4 o;
            o.x = pack_bf2(ov[16 * h + 0], ov[16 * h + 1]);
            o.y = pack_bf2(ov[16 * h + 2], ov[16 * h + 3]);
            o.z = pack_bf2(ov[16 * h + 4], ov[16 * h + 5]);
            o.w = pack_bf2(ov[16 * h + 6], ov[16 * h + 7]);
            orow[2 * h] = o;
            o.x = pack_bf2(ov[16 * h + 8], ov[16 * h + 9]);
            o.y = pack_bf2(ov[16 * h + 10], ov[16 * h + 11]);
            o.z = pack_bf2(ov[16 * h + 12], ov[16 * h + 13]);
            o.w = pack_bf2(ov[16 * h + 14], ov[16 * h + 15]);
            orow[2 * h + 1] = o;
        }
    }
}

// ---- critic: block 64 rows x 128 cols, wave 32x64, acc[2][4] ------------
// batch-major inputs: X rows at stride 16*256 B (256 B contiguous chunks).
__global__ __launch_bounds__(256, 4) void k_critic(
    const unsigned* __restrict__ se_u, const unsigned* __restrict__ other_u,
    const unsigned* __restrict__ wt_cr,
    const float* __restrict__ bc1, const float* __restrict__ actions,
    const float* __restrict__ wt_c2, const float* __restrict__ bc2,
    float* __restrict__ qout, int b0g, int Bc) {
    __shared__ unsigned smem[(64 + 128) * 34];
    unsigned* Xs = smem;
    unsigned* Ws = smem + 64 * 34;

    int a = blockIdx.y;
    int b0 = blockIdx.x * 64;
    int t = threadIdx.x;
    int wid = t >> 6, lane = t & 63, lm = lane & 15, lq = lane >> 4;
    int wrow = (wid & 1) * 32;
    int wcol = (wid >> 1) * 64;

    floatx4 acc[2][4];
#pragma unroll
    for (int mt = 0; mt < 2; ++mt)
#pragma unroll
        for (int nt = 0; nt < 4; ++nt)
#pragma unroll
            for (int e = 0; e < 4; ++e) acc[mt][nt][e] = 0.f;

    const unsigned* WtA = wt_cr + (size_t)a * 16384;

    for (int c = 0; c < 4; ++c) {
        int kk = c * 64;
        __syncthreads();
        const unsigned* src = (c < 2) ? se_u : other_u;
        int off = (c & 1) * 32;
        for (int idx = t; idx < 64 * 8; idx += 256) {
            int r = idx >> 3, c4 = idx & 7;
            uint4 v = *(const uint4*)&src[((size_t)(b0 + r) * 16 + a) * 64 + off + c4 * 4];
            uint2* dst = (uint2*)&Xs[r * 34 + c4 * 4];
            dst[0] = make_uint2(v.x, v.y);
            dst[1] = make_uint2(v.z, v.w);
        }
        for (int idx = t; idx < 128 * 8; idx += 256) {
            int n = idx >> 3, c4 = idx & 7;
            uint4 w = *(const uint4*)&WtA[(size_t)n * 128 + (kk >> 1) + c4 * 4];
            uint2* dst = (uint2*)&Ws[n * 34 + c4 * 4];
            dst[0] = make_uint2(w.x, w.y);
            dst[1] = make_uint2(w.z, w.w);
        }
        __syncthreads();
#pragma unroll
        for (int s = 0; s < 2; ++s) {
            short8 afr[2];
#pragma unroll
            for (int mt = 0; mt < 2; ++mt)
                afr[mt] = ld_frag(&Xs[(wrow + mt * 16 + lm) * 34 + s * 16 + lq * 4]);
#pragma unroll
            for (int nt = 0; nt < 4; ++nt) {
                short8 bfr = ld_frag(&Ws[(wcol + nt * 16 + lm) * 34 + s * 16 + lq * 4]);
#pragma unroll
                for (int mt = 0; mt < 2; ++mt)
                    acc[mt][nt] = __builtin_amdgcn_mfma_f32_16x16x32_bf16(
                        afr[mt], bfr, acc[mt][nt], 0, 0, 0);
            }
        }
    }

    __syncthreads();
    unsigned short* hbuf = (unsigned short*)smem;  // [64][132]
#pragma unroll
    for (int mt = 0; mt < 2; ++mt)
#pragma unroll
        for (int nt = 0; nt < 4; ++nt)
#pragma unroll
            for (int r = 0; r < 4; ++r) {
                int row = wrow + mt * 16 + lq * 4 + r;
                int col = wcol + nt * 16 + lm;
                float v = acc[mt][nt][r] + bc1[a * H_N + col];
                v = v > 0.f ? v : 0.01f * v;
                hbuf[row * 132 + col] = f2bf(v);
            }
    __syncthreads();
    if (t < 64) {
        size_t arow = (size_t)a * B_N + b0g + b0 + t;
        const float* ap = &actions[arow * ACT_N];
        float bestv = ap[0];
        int bi = 0;
        for (int o = 1; o < ACT_N; ++o) {
            float v = ap[o];
            if (v > bestv) { bestv = v; bi = o; }
        }
        float q = bc2[a * ACT_N + bi];
        const float4* w4p = (const float4*)&wt_c2[((size_t)a * ACT_N + bi) * H_N];
        const uint2* hp2 = (const uint2*)&hbuf[t * 132];
#pragma unroll
        for (int h4 = 0; h4 < 32; ++h4) {
            float4 w4 = w4p[h4];
            uint2 hh = hp2[h4];
            q = fmaf(bflo(hh.x), w4.x, q);
            q = fmaf(bfhi(hh.x), w4.y, q);
            q = fmaf(bflo(hh.y), w4.z, q);
            q = fmaf(bfhi(hh.y), w4.w, q);
        }
        qout[arow] = q;
    }
}

extern "C" void kernel_launch(void* const* d_in, const int* in_sizes, int n_in,
                              void* d_out, int out_size, void* d_ws, size_t ws_size,
                              hipStream_t stream) {
    const float* obs     = (const float*)d_in[0];
    const float* actions = (const float*)d_in[1];
    const float* W_sa    = (const float*)d_in[2];
    const float* b_sa    = (const float*)d_in[3];
    const float* W_s     = (const float*)d_in[4];
    const float* b_s     = (const float*)d_in[5];
    const float* Wk      = (const float*)d_in[6];
    const float* Wsel    = (const float*)d_in[7];
    const float* Wv      = (const float*)d_in[8];
    const float* bv      = (const float*)d_in[9];
    const float* Wc1     = (const float*)d_in[10];
    const float* bc1     = (const float*)d_in[11];
    const float* Wc2     = (const float*)d_in[12];
    const float* bc2     = (const float*)d_in[13];
    float* out = (float*)d_out;
    char* ws = (char*)d_ws;

    size_t o = 0;
    float* gsum = (float*)(ws + o); o += 2304 * 4;
    float* gsq  = (float*)(ws + o); o += 2304 * 4;
    unsigned* wt_l1 = (unsigned*)(ws + o); o += (size_t)393216 * 4;
    unsigned* wt_p1 = (unsigned*)(ws + o); o += (size_t)16384 * 4;
    unsigned* wt_p2 = (unsigned*)(ws + o); o += (size_t)8192 * 4;
    unsigned* wt_cr = (unsigned*)(ws + o); o += (size_t)262144 * 4;
    float* fb = (float*)(ws + o); o += (size_t)4096 * 4;
    float* wt_c2 = (float*)(ws + o); o += (size_t)32768 * 4;
    size_t fixed = o;

    int Bc = B_N;
    while (Bc > 128 && fixed + 12288ull * Bc > ws_size) Bc >>= 1;

    unsigned short* sa_us = (unsigned short*)(ws + o); o += (size_t)A_N * Bc * 128 * 2;
    unsigned short* se_us = (unsigned short*)(ws + o); o += (size_t)A_N * Bc * 128 * 2;
    unsigned short* ot_us = (unsigned short*)(ws + o); o += (size_t)A_N * Bc * 128 * 2;

    k_zero<<<dim3(18), 256, 0, stream>>>(gsum, 2 * A_N * IN_N);
    k_stats<<<dim3(A_N * 32), 256, 0, stream>>>(obs, actions, gsum, gsq);
    k_finalize<<<dim3(9), 256, 0, stream>>>(gsum, gsq);
    k_wprep<<<dim3(C2E / 256), 256, 0, stream>>>(W_sa, W_s, Wk, Wsel, Wv, Wc1, Wc2,
                                                 gsq, wt_l1, wt_p1, wt_p2, wt_cr, wt_c2);
    k_bfold<<<dim3(A_N), 256, 0, stream>>>(gsum, gsq, W_sa, W_s, b_sa, b_s, fb);

    for (int b0g = 0; b0g < B_N; b0g += Bc) {
        k_l1<<<dim3(Bc / 128, A_N), 512, 0, stream>>>(
            obs, actions, wt_l1, fb, sa_us, se_us, b0g, Bc);
        k_fused<<<dim3(Bc / 4), 256, 0, stream>>>(
            (const unsigned*)sa_us, (const unsigned*)se_us, wt_p1, wt_p2, bv,
            ot_us, Bc);
        k_critic<<<dim3(Bc / 64, A_N), 256, 0, stream>>>(
            (const unsigned*)se_us, (const unsigned*)ot_us, wt_cr, bc1,
            actions, wt_c2, bc2, out, b0g, Bc);
    }
}